// Round 9
// baseline (274.140 us; speedup 1.0000x reference)
//
#include <hip/hip_runtime.h>

// SpecNCutout: out = select(mask, mean(x), x)
// x: (B=128, H=256, W=1024, C=1) fp32. mask = union of 5 clipped rects/batch.
//
// R9: discriminating probe. R4/R7/R8's copies all pinned at ~85us despite
// different structures (conditional/unconditional stores, 1/8-deep MLP) ->
// shared-resource suspicion: the 536MB harness poison fill right before us
// is timed at LLC-acceptance rate and its dirty-line drain lands in OUR
// window (structure-independent ~constant tax). This round splits the work
// into three separately-profiled dispatches:
//  (a) reduce-only: EXACT R8 access pattern minus the stores ->
//      bit-identical partials -> bit-identical mean (absmax 0.0 preserved)
//  (b) hipMemcpyAsync D2D x->out: the runtime's tuned blit path (same
//      machinery class as the 6.2TB/s fill) does the bulk copy
//  (c) fill_holes: unchanged (overwrites hole spans with mean; stream
//      order guarantees it lands after the memcpy)
// Counters will show whether (a) is latency/structure-bound (fast now) or
// drain-taxed (slow regardless) and whether the blit hits full BW.

#define BB 128
#define HH 256
#define WW 1024
#define N_HOLES 5
#define HOLE_MINW (WW / 10)   // 102
#define HOLE_MINH (HH / 10)   // 25
#define N_ELEM (BB * HH * WW) // 33554432
#define ROWS_PER_BLOCK 16
#define RED_BLOCKS (BB * HH / ROWS_PER_BLOCK)  // 2048
#define ROW_SLICES 8
#define BATCH_ROWS 8          // independent loads in flight per wave

// Pass (a): reduce-only. Identical per-thread load set + accumulation order
// to R8's copy_reduce -> partials bit-identical.
__global__ __launch_bounds__(256) void reduce_kernel(
    const float* __restrict__ x, float* __restrict__ partials) {
  int blk = blockIdx.x;
  int row0 = blk * ROWS_PER_BLOCK;
  int tid = threadIdx.x;

  const float4* x4 = (const float4*)x;

  float s = 0.0f;
  #pragma unroll
  for (int g = 0; g < ROWS_PER_BLOCK / BATCH_ROWS; ++g) {   // 2 chunks
    float4 v[BATCH_ROWS];
    #pragma unroll
    for (int r = 0; r < BATCH_ROWS; ++r) {
      long i = (long)(row0 + g * BATCH_ROWS + r) * (WW / 4) + tid;
      v[r] = x4[i];
    }
    #pragma unroll
    for (int r = 0; r < BATCH_ROWS; ++r) {
      s += (v[r].x + v[r].y) + (v[r].z + v[r].w);
    }
  }

  #pragma unroll
  for (int off = 32; off > 0; off >>= 1) s += __shfl_down(s, off, 64);
  __shared__ float wsum[4];
  int lane = tid & 63;
  int wave = tid >> 6;
  if (lane == 0) wsum[wave] = s;
  __syncthreads();
  if (tid == 0)
    partials[blockIdx.x] = (wsum[0] + wsum[1]) + (wsum[2] + wsum[3]);
}

// Pass (c) (verbatim R4): write mean into hole spans. One block per
// (batch, hole, row-slice). Each block privately reduces the 2048 partials
// (8 KiB, L2-broadcast) with the identical tree -> bit-identical mean.
__global__ __launch_bounds__(256) void fill_holes_kernel(
    const int* __restrict__ xs, const int* __restrict__ ys,
    const int* __restrict__ xs_w_raw, const int* __restrict__ ys_h_raw,
    const float* __restrict__ act_rand,
    const float* __restrict__ partials,
    float* __restrict__ out) {
  float s = 0.0f;
  for (int i = threadIdx.x; i < RED_BLOCKS; i += 256) s += partials[i];
  #pragma unroll
  for (int off = 32; off > 0; off >>= 1) s += __shfl_down(s, off, 64);
  __shared__ float wsum[4];
  __shared__ float mean_sh;
  int lane = threadIdx.x & 63;
  int wave = threadIdx.x >> 6;
  if (lane == 0) wsum[wave] = s;
  __syncthreads();
  if (threadIdx.x == 0) {
    float t = (wsum[0] + wsum[1]) + (wsum[2] + wsum[3]);
    mean_sh = t * (1.0f / (float)N_ELEM);
  }
  __syncthreads();
  float mean = mean_sh;

  int bid = blockIdx.x;
  int b = bid / (N_HOLES * ROW_SLICES);
  int rem = bid % (N_HOLES * ROW_SLICES);
  int n = rem / ROW_SLICES;
  int slice = rem % ROW_SLICES;

  int base = b * N_HOLES + n;
  if (!(act_rand[base] < 1.0f)) return;          // PROB = 1.0, always true
  int cx = xs[base];
  int cy = ys[base];
  int hw = (xs_w_raw[base] + HOLE_MINW) >> 1;
  int hh = (ys_h_raw[base] + HOLE_MINH) >> 1;
  int ys_s = min(max(cy - hh, 0), HH - 2);
  int ys_e = min(max(cy + hh, 1), HH - 1);
  int xs_s = min(max(cx - hw, 0), WW - 2);
  int xs_e = min(max(cx + hw, 1), WW - 1);

  // Overlapping holes double-write the same bit pattern: race-free.
  for (int h = ys_s + slice; h <= ys_e; h += ROW_SLICES) {
    long rowbase = (long)(b * HH + h) * WW;
    for (int w = xs_s + (int)threadIdx.x; w <= xs_e; w += 256) {
      out[rowbase + w] = mean;
    }
  }
}

extern "C" void kernel_launch(void* const* d_in, const int* in_sizes, int n_in,
                              void* d_out, int out_size, void* d_ws, size_t ws_size,
                              hipStream_t stream) {
  const float* x        = (const float*)d_in[0];
  const int* xs         = (const int*)d_in[1];
  const int* ys         = (const int*)d_in[2];
  const int* xs_w_raw   = (const int*)d_in[3];
  const int* ys_h_raw   = (const int*)d_in[4];
  const float* act_rand = (const float*)d_in[5];
  float* out = (float*)d_out;

  float* partials = (float*)d_ws;                // RED_BLOCKS floats

  // (a) reduce-only (bit-identical partials to R8)
  reduce_kernel<<<RED_BLOCKS, 256, 0, stream>>>(x, partials);
  // (b) bulk copy via the runtime's tuned blit path (stream-ordered)
  hipMemcpyAsync(out, x, (size_t)N_ELEM * sizeof(float),
                 hipMemcpyDeviceToDevice, stream);
  // (c) overwrite hole spans with mean
  fill_holes_kernel<<<BB * N_HOLES * ROW_SLICES, 256, 0, stream>>>(
      xs, ys, xs_w_raw, ys_h_raw, act_rand, partials, out);
}

// Round 10
// 273.265 us; speedup vs baseline: 1.0032x; 1.0032x over previous
//
#include <hip/hip_runtime.h>

// SpecNCutout: out = select(mask, mean(x), x)
// x: (B=128, H=256, W=1024, C=1) fp32. mask = union of 5 clipped rects/batch.
//
// R10: LLC-residency play. x (134 MB) fits in the 256 MB L3.
//  Pass 1 (reduce-only, NO writes): warms L3 with all of x while computing
//    the 2048 partials (bit-identical order to R8/R9 -> bit-identical mean).
//  Pass 2 (apply): per block computes mean from partials (R4's exact tree),
//    reads x (mostly L3 hits now -> low FETCH), computes the exact per-pixel
//    select, and writes out with UNCONDITIONAL full-line float4 stores at
//    fill-rate. Blocks iterate rows in REVERSE order (MRU-first) to read the
//    most-recently-cached part of x before any eviction catches up.
// HBM traffic is exactly minimal: 134 MB read + 134 MB write.
// Discriminator: apply's FETCH_SIZE << 65 MB confirms L3 residency.

#define BB 128
#define HH 256
#define WW 1024
#define N_HOLES 5
#define HOLE_MINW (WW / 10)   // 102
#define HOLE_MINH (HH / 10)   // 25
#define N_ELEM (BB * HH * WW) // 33554432
#define ROWS_PER_BLOCK 16
#define RED_BLOCKS (BB * HH / ROWS_PER_BLOCK)  // 2048
#define BATCH_ROWS 8          // independent loads in flight per wave

// Pass 1: reduce-only. Identical per-thread load set + accumulation order
// to R8/R9 -> partials bit-identical. Read-only => L3 ends holding x.
__global__ __launch_bounds__(256) void reduce_kernel(
    const float* __restrict__ x, float* __restrict__ partials) {
  int blk = blockIdx.x;
  int row0 = blk * ROWS_PER_BLOCK;
  int tid = threadIdx.x;

  const float4* x4 = (const float4*)x;

  float s = 0.0f;
  #pragma unroll
  for (int g = 0; g < ROWS_PER_BLOCK / BATCH_ROWS; ++g) {   // 2 chunks
    float4 v[BATCH_ROWS];
    #pragma unroll
    for (int r = 0; r < BATCH_ROWS; ++r) {
      long i = (long)(row0 + g * BATCH_ROWS + r) * (WW / 4) + tid;
      v[r] = x4[i];
    }
    #pragma unroll
    for (int r = 0; r < BATCH_ROWS; ++r) {
      s += (v[r].x + v[r].y) + (v[r].z + v[r].w);
    }
  }

  #pragma unroll
  for (int off = 32; off > 0; off >>= 1) s += __shfl_down(s, off, 64);
  __shared__ float wsum[4];
  int lane = tid & 63;
  int wave = tid >> 6;
  if (lane == 0) wsum[wave] = s;
  __syncthreads();
  if (tid == 0)
    partials[blockIdx.x] = (wsum[0] + wsum[1]) + (wsum[2] + wsum[3]);
}

// Pass 2: full select-write. mean via R4's exact reduction tree (8 KiB of
// L2-broadcast partials per block); exact per-pixel mask; unconditional
// full-line stores. Reverse block->row mapping for MRU-first L3 reads.
__global__ __launch_bounds__(256) void apply_kernel(
    const float* __restrict__ x,
    const int* __restrict__ xs, const int* __restrict__ ys,
    const int* __restrict__ xs_w_raw, const int* __restrict__ ys_h_raw,
    const float* __restrict__ act_rand,
    const float* __restrict__ partials,
    float* __restrict__ out) {
  int tid = threadIdx.x;
  int lane = tid & 63;
  int wave = tid >> 6;
  __shared__ float wsum[4];
  __shared__ float mean_sh;

  // mean from partials (bit-identical tree to previous passing rounds)
  {
    float s = 0.0f;
    for (int i = tid; i < RED_BLOCKS; i += 256) s += partials[i];
    #pragma unroll
    for (int off = 32; off > 0; off >>= 1) s += __shfl_down(s, off, 64);
    if (lane == 0) wsum[wave] = s;
    __syncthreads();
    if (tid == 0) {
      float t = (wsum[0] + wsum[1]) + (wsum[2] + wsum[3]);
      mean_sh = t * (1.0f / (float)N_ELEM);
    }
    __syncthreads();
  }
  float mean = mean_sh;

  // Reverse mapping: last-read rows of x are processed first (MRU in L3).
  int blk = (RED_BLOCKS - 1) - blockIdx.x;
  int b = blk >> 4;                 // 16 blocks per batch
  int row0 = blk * ROWS_PER_BLOCK;
  int w0 = tid * 4;                 // W=1024 = 256 threads * 4

  // Per-block (batch-uniform) hole rects.
  int ys_s[N_HOLES], ys_e[N_HOLES], xlo[N_HOLES], xhi[N_HOLES];
  #pragma unroll
  for (int n = 0; n < N_HOLES; ++n) {
    int base = b * N_HOLES + n;
    int cx = xs[base];
    int cy = ys[base];
    int hw = (xs_w_raw[base] + HOLE_MINW) >> 1;  // xs_w // 2
    int hh = (ys_h_raw[base] + HOLE_MINH) >> 1;  // ys_h // 2
    bool act = act_rand[base] < 1.0f;            // PROB = 1.0
    int yss = min(max(cy - hh, 0), HH - 2);
    int yse = min(max(cy + hh, 1), HH - 1);
    ys_s[n] = act ? yss : 1;
    ys_e[n] = act ? yse : 0;                     // empty if inactive
    xlo[n] = min(max(cx - hw, 0), WW - 2);
    xhi[n] = min(max(cx + hw, 1), WW - 1);
  }

  const float4* x4 = (const float4*)x;
  float4* out4 = (float4*)out;

  #pragma unroll
  for (int g = 0; g < ROWS_PER_BLOCK / BATCH_ROWS; ++g) {   // 2 chunks
    float4 v[BATCH_ROWS];
    #pragma unroll
    for (int r = 0; r < BATCH_ROWS; ++r) {
      long i = (long)(row0 + g * BATCH_ROWS + r) * (WW / 4) + tid;
      v[r] = x4[i];
    }
    #pragma unroll
    for (int r = 0; r < BATCH_ROWS; ++r) {
      int row = row0 + g * BATCH_ROWS + r;
      int h = row & (HH - 1);
      float rv[4] = {v[r].x, v[r].y, v[r].z, v[r].w};
      #pragma unroll
      for (int j = 0; j < 4; ++j) {
        int w = w0 + j;
        bool m = false;
        #pragma unroll
        for (int n = 0; n < N_HOLES; ++n)
          m = m || ((ys_s[n] <= h) && (h <= ys_e[n]) &&
                    (xlo[n] <= w) && (w <= xhi[n]));
        if (m) rv[j] = mean;
      }
      float4 o;
      o.x = rv[0]; o.y = rv[1]; o.z = rv[2]; o.w = rv[3];
      long i = (long)row * (WW / 4) + tid;
      out4[i] = o;                               // unconditional full-line
    }
  }
}

extern "C" void kernel_launch(void* const* d_in, const int* in_sizes, int n_in,
                              void* d_out, int out_size, void* d_ws, size_t ws_size,
                              hipStream_t stream) {
  const float* x        = (const float*)d_in[0];
  const int* xs         = (const int*)d_in[1];
  const int* ys         = (const int*)d_in[2];
  const int* xs_w_raw   = (const int*)d_in[3];
  const int* ys_h_raw   = (const int*)d_in[4];
  const float* act_rand = (const float*)d_in[5];
  float* out = (float*)d_out;

  float* partials = (float*)d_ws;                // RED_BLOCKS floats

  reduce_kernel<<<RED_BLOCKS, 256, 0, stream>>>(x, partials);
  apply_kernel<<<RED_BLOCKS, 256, 0, stream>>>(
      x, xs, ys, xs_w_raw, ys_h_raw, act_rand, partials, out);
}